// Round 22
// baseline (213.700 us; speedup 1.0000x reference)
//
#include <hip/hip_runtime.h>
#include <hip/hip_bf16.h>
#include <stdint.h>

#define Ss   1024
#define MEMm 1024
#define Tt   2048
#define Dd   1024
#define Hh   16
#define DKk  64

typedef unsigned short u16;
using f32x4 = __attribute__((ext_vector_type(4))) float;
using s16x8 = __attribute__((ext_vector_type(8))) short;

__device__ __forceinline__ u16 f2bf(float x) {
  __hip_bfloat16 h = __float2bfloat16(x);
  return *(reinterpret_cast<u16*>(&h));
}
__device__ __forceinline__ float b2f(short s) {
  union { uint32_t u; float f; } c; c.u = ((uint32_t)(u16)s) << 16; return c.f;
}
__device__ __forceinline__ uint32_t pk2(float lo, float hi) {
  return (uint32_t)f2bf(lo) | ((uint32_t)f2bf(hi) << 16);
}
__device__ __forceinline__ f32x4 mfma16(s16x8 a, s16x8 b, f32x4 c) {
  return __builtin_amdgcn_mfma_f32_16x16x32_bf16(a, b, c, 0, 0, 0);
}
__device__ __forceinline__ void gl_lds16(const u16* g, u16* l) {
  __builtin_amdgcn_global_load_lds(
      (const __attribute__((address_space(1))) uint32_t*)g,
      (__attribute__((address_space(3))) uint32_t*)l, 16, 0, 0);
}

// ---------------------------------------------------------------------------
// Weight conversion only (activations consumed as f32 directly by gemm_all).
// ---------------------------------------------------------------------------
__global__ __launch_bounds__(256)
void cvt5w(const float* __restrict__ w0, const float* __restrict__ w1,
           const float* __restrict__ w2, const float* __restrict__ w3,
           const float* __restrict__ w4, u16* __restrict__ Wb) {
  const float* s;
  switch (blockIdx.y) {
    case 0: s = w0; break; case 1: s = w1; break; case 2: s = w2; break;
    case 3: s = w3; break; default: s = w4; break;
  }
  const int idx = blockIdx.x * 256 + threadIdx.x;
  const float4* p = (const float4*)(s + (size_t)idx * 8);
  const float4 a = p[0], bq = p[1];
  uint4 o;
  o.x = pk2(a.x, a.y);   o.y = pk2(a.z, a.w);
  o.z = pk2(bq.x, bq.y); o.w = pk2(bq.z, bq.w);
  *(uint4*)(Wb + ((size_t)blockIdx.y << 20) + (size_t)idx * 8) = o;
}

// ---------------------------------------------------------------------------
// Shared GEMM epilogue.  EPI: 0=QH, 1=KH, 2=VT(transposed), 3=RH, 4=fp32 out
// ---------------------------------------------------------------------------
template <int EPI>
__device__ __forceinline__
void gemm_epi(f32x4 (&acc)[4][4], void* __restrict__ O, int n0, int m0) {
  const int lane = threadIdx.x & 63, wave = threadIdx.x >> 6;
  const int fr = lane & 15, fq = lane >> 4;
  const int wr = (wave >> 1) * 64, wc = (wave & 1) * 64;
#pragma unroll
  for (int i = 0; i < 4; ++i)
#pragma unroll
    for (int j = 0; j < 4; ++j) {
      if constexpr (EPI == 2) {
        const int grow = n0 + wr + i * 16 + fq * 4;
        const int m = m0 + wc + j * 16 + fr;
        const int bb = grow >> 11, t = grow & 2047;
        const int hh = m >> 6, dk = m & 63;
        ushort4 pk4;
        pk4.x = f2bf(acc[i][j][0]); pk4.y = f2bf(acc[i][j][1]);
        pk4.z = f2bf(acc[i][j][2]); pk4.w = f2bf(acc[i][j][3]);
        *(ushort4*)&((u16*)O)[(((size_t)(bb * Hh + hh) * DKk + dk) << 11) + t] = pk4;
      } else {
#pragma unroll
        for (int r = 0; r < 4; ++r) {
          const int n = n0 + wr + i * 16 + fq * 4 + r;
          const int m = m0 + wc + j * 16 + fr;
          const float y = acc[i][j][r];
          if constexpr (EPI == 0) {
            const int bb = n >> 10, s = n & 1023, hh = m >> 6, dk = m & 63;
            ((u16*)O)[((size_t)(bb * Hh + hh) * Ss + s) * DKk + dk] = f2bf(y);
          } else if constexpr (EPI == 1) {
            const int bb = n >> 11, t = n & 2047, hh = m >> 6, dk = m & 63;
            ((u16*)O)[((size_t)(bb * Hh + hh) * Tt + t) * DKk + dk] = f2bf(y);
          } else if constexpr (EPI == 3) {
            const int hh = m >> 6, dk = m & 63;
            ((u16*)O)[((size_t)hh * Tt + n) * DKk + dk] = f2bf(y);
          } else {
            ((float*)O)[(size_t)n * Dd + m] = y;
          }
        }
      }
    }
}

// ---------------------------------------------------------------------------
// fp32-A body, BK=64, with HALF-PREFETCH: panels 0-1 of the NEXT K-step are
// loaded right after the staging barrier so their latency hides under the
// MFMA phase (drained by the phase-end barrier). Panels 2-3 load at top.
// 16 extra VGPR live across MFMA (acc64+fn16+frags32+addr ~= 120 <= 128 cap).
// A: contiguous ds_write_b128 (conflict-free), parity XOR write & read.
// B: 4 pre-swizzled gl_lds (bf16 weights).
// ---------------------------------------------------------------------------
template <int EPI>
__device__ __forceinline__
void gemm_body_f32(const float* __restrict__ X, const u16* __restrict__ W,
                   void* __restrict__ O, int n0, int m0, u16* As, u16* Bs) {
  const int tid = threadIdx.x;
  const int lane = tid & 63, wave = tid >> 6;
  const int fr = lane & 15, fq = lane >> 4;
  const int wr = (wave >> 1) * 64, wc = (wave & 1) * 64;
  f32x4 acc[4][4] = {};

  const int arow8 = tid >> 3;        // 0..31
  const int aseg  = tid & 7;         // 0..7
  const int lrow8 = lane >> 3;       // 0..7 (B staging)
  const int lcol  = (lane & 7) * 8;

  const float* xbase = X + (size_t)(n0 + arow8) * Dd + aseg * 8;

  // prologue: prefetch panels 0,1 for k0 = 0
  float4 fn[2][2];
#pragma unroll
  for (int p = 0; p < 2; ++p) {
    const float* src = xbase + (size_t)(p * 32) * Dd;
    fn[p][0] = *(const float4*)src;
    fn[p][1] = *(const float4*)(src + 4);
  }

  for (int k0 = 0; k0 < Dd; k0 += 64) {
    // load panels 2,3 for current k0 (not prefetched)
    float4 fa[2][2];
#pragma unroll
    for (int p = 0; p < 2; ++p) {
      const float* src = xbase + (size_t)((p + 2) * 32) * Dd + k0;
      fa[p][0] = *(const float4*)src;
      fa[p][1] = *(const float4*)(src + 4);
    }
    // B staging via gl_lds
#pragma unroll
    for (int p = 0; p < 4; ++p) {
      const int row = p * 32 + wave * 8 + lrow8;
      const int scol = lcol ^ ((row & 1) * 32);
      gl_lds16(W + (size_t)(m0 + row) * Dd + k0 + scol,
               &Bs[(p * 32 + wave * 8) * 64]);
    }
    // A cvt + conflict-free ds_write: panels 0,1 from fn; 2,3 from fa
#pragma unroll
    for (int p = 0; p < 2; ++p) {
      const int row = p * 32 + arow8;
      uint4 pk4;
      pk4.x = pk2(fn[p][0].x, fn[p][0].y);
      pk4.y = pk2(fn[p][0].z, fn[p][0].w);
      pk4.z = pk2(fn[p][1].x, fn[p][1].y);
      pk4.w = pk2(fn[p][1].z, fn[p][1].w);
      *(uint4*)&As[row * 64 + ((aseg * 8) ^ ((row & 1) * 32))] = pk4;
    }
#pragma unroll
    for (int p = 0; p < 2; ++p) {
      const int row = (p + 2) * 32 + arow8;
      uint4 pk4;
      pk4.x = pk2(fa[p][0].x, fa[p][0].y);
      pk4.y = pk2(fa[p][0].z, fa[p][0].w);
      pk4.z = pk2(fa[p][1].x, fa[p][1].y);
      pk4.w = pk2(fa[p][1].z, fa[p][1].w);
      *(uint4*)&As[row * 64 + ((aseg * 8) ^ ((row & 1) * 32))] = pk4;
    }
    __syncthreads();  // staging visible (drains vmcnt incl. gl_lds)

    // prefetch panels 0,1 for NEXT k0 — latency hides under the MFMA phase
    const bool more = (k0 + 64 < Dd);
    if (more) {
#pragma unroll
      for (int p = 0; p < 2; ++p) {
        const float* src = xbase + (size_t)(p * 32) * Dd + (k0 + 64);
        fn[p][0] = *(const float4*)src;
        fn[p][1] = *(const float4*)(src + 4);
      }
    }

#pragma unroll
    for (int kc = 0; kc < 2; ++kc) {
      s16x8 af[4], bfv[4];
#pragma unroll
      for (int i = 0; i < 4; ++i) {
        const int row = wr + i * 16 + fr;
        af[i] = *(const s16x8*)&As[row * 64 + ((kc * 32 + fq * 8) ^ ((row & 1) * 32))];
      }
#pragma unroll
      for (int j = 0; j < 4; ++j) {
        const int row = wc + j * 16 + fr;
        bfv[j] = *(const s16x8*)&Bs[row * 64 + ((kc * 32 + fq * 8) ^ ((row & 1) * 32))];
      }
#pragma unroll
      for (int i = 0; i < 4; ++i)
#pragma unroll
        for (int j = 0; j < 4; ++j)
          acc[i][j] = mfma16(af[i], bfv[j], acc[i][j]);
    }
    __syncthreads();  // reads done; also drains the fn prefetch
  }
  gemm_epi<EPI>(acc, O, n0, m0);
}

// ---------------------------------------------------------------------------
// All four projections in ONE dispatch (1408 blocks), f32-A BK=64 path,
// XCD-bijective swizzle (1408 = 8 x 176).
// ---------------------------------------------------------------------------
__global__ __launch_bounds__(256, 2)
void gemm_all(const float* __restrict__ kf, const float* __restrict__ vf,
              const float* __restrict__ qf, const float* __restrict__ Rf,
              const u16* __restrict__ Wb,
              u16* __restrict__ QH, u16* __restrict__ KH,
              u16* __restrict__ VT, u16* __restrict__ RH) {
  __shared__ u16 As[128 * 64];
  __shared__ u16 Bs[128 * 64];
  const int bid = (blockIdx.x & 7) * 176 + (blockIdx.x >> 3);  // XCD swizzle
  if (bid < 512) {
    const int t = bid;
    gemm_body_f32<1>(kf, Wb + ((size_t)1 << 20), KH,
                     (t >> 3) * 128, (t & 7) * 128, As, Bs);
  } else if (bid < 1024) {
    const int t = bid - 512;
    gemm_body_f32<2>(vf, Wb + ((size_t)2 << 20), VT,
                     (t >> 3) * 128, (t & 7) * 128, As, Bs);
  } else if (bid < 1280) {
    const int t = bid - 1024;
    gemm_body_f32<0>(qf, Wb, QH, (t >> 3) * 128, (t & 7) * 128, As, Bs);
  } else {
    const int t = bid - 1280;
    gemm_body_f32<3>(Rf, Wb + ((size_t)3 << 20), RH,
                     (t >> 3) * 128, (t & 7) * 128, As, Bs);
  }
}

// ---------------------------------------------------------------------------
// o-projection (fp32 out), 128x64 tiles -> 512 blocks = 2 blocks/CU.
// BK=64 + parity XOR swizzle, acc[4][2]. XCD swizzle 512 = 8 x 64.
// Byte-identical to rounds 18-21.
// ---------------------------------------------------------------------------
__global__ __launch_bounds__(256, 2)
void gemm_o(const u16* __restrict__ X, const u16* __restrict__ W,
            float* __restrict__ O) {
  __shared__ u16 As[128 * 64];
  __shared__ u16 Bs[64 * 64];
  const int t = (blockIdx.x & 7) * 64 + (blockIdx.x >> 3);  // XCD swizzle
  const int n0 = (t >> 4) * 128;   // 32 n-tiles
  const int m0 = (t & 15) * 64;    // 16 m-tiles
  const int tid = threadIdx.x;
  const int lane = tid & 63, wave = tid >> 6;
  const int fr = lane & 15, fq = lane >> 4;
  const int wr = (wave >> 1) * 64, wc = (wave & 1) * 32;
  f32x4 acc[4][2] = {};

  const int lrow8 = lane >> 3;
  const int lcol  = (lane & 7) * 8;

  for (int k0 = 0; k0 < Dd; k0 += 64) {
#pragma unroll
    for (int p = 0; p < 4; ++p) {
      const int row = p * 32 + wave * 8 + lrow8;
      const int scol = lcol ^ ((row & 1) * 32);
      gl_lds16(X + (size_t)(n0 + row) * Dd + k0 + scol, &As[(p * 32 + wave * 8) * 64]);
    }
#pragma unroll
    for (int p = 0; p < 2; ++p) {
      const int row = p * 32 + wave * 8 + lrow8;
      const int scol = lcol ^ ((row & 1) * 32);
      gl_lds16(W + (size_t)(m0 + row) * Dd + k0 + scol, &Bs[(p * 32 + wave * 8) * 64]);
    }
    __syncthreads();
#pragma unroll
    for (int kc = 0; kc < 2; ++kc) {
      s16x8 af[4], bfv[2];
#pragma unroll
      for (int i = 0; i < 4; ++i) {
        const int row = wr + i * 16 + fr;
        af[i] = *(const s16x8*)&As[row * 64 + ((kc * 32 + fq * 8) ^ ((row & 1) * 32))];
      }
#pragma unroll
      for (int j = 0; j < 2; ++j) {
        const int row = wc + j * 16 + fr;
        bfv[j] = *(const s16x8*)&Bs[row * 64 + ((kc * 32 + fq * 8) ^ ((row & 1) * 32))];
      }
#pragma unroll
      for (int i = 0; i < 4; ++i)
#pragma unroll
        for (int j = 0; j < 2; ++j)
          acc[i][j] = mfma16(af[i], bfv[j], acc[i][j]);
    }
    __syncthreads();
  }

#pragma unroll
  for (int i = 0; i < 4; ++i)
#pragma unroll
    for (int j = 0; j < 2; ++j)
#pragma unroll
      for (int r = 0; r < 4; ++r) {
        const int n = n0 + wr + i * 16 + fq * 4 + r;
        const int m = m0 + wc + j * 16 + fr;
        O[(size_t)n * Dd + m] = acc[i][j][r];
      }
}

// ---------------------------------------------------------------------------
// Fused TXL attention v14 (proven: ring-race-free BD-at-tail pipelining,
// SC folded into Q frags, defer-max, (256,2) VGPR cap).
// Byte-identical to rounds 16-21.
// ---------------------------------------------------------------------------
__global__ __launch_bounds__(256, 2)
void attn14(const u16* __restrict__ QH, const u16* __restrict__ KH,
            const u16* __restrict__ VT, const u16* __restrict__ RH,
            const float* __restrict__ ub, const float* __restrict__ vbb,
            u16* __restrict__ CONCAT) {
  __shared__ u16 Ks[64 * 64];
  __shared__ u16 Vt[64 * 64];
  __shared__ u16 RB[256 * 64];
  __shared__ u16 Pl[4][2][16 * 72];

  const int tid = threadIdx.x;
  const int wave = tid >> 6, lane = tid & 63;
  const int fr = lane & 15, fq = lane >> 4;

  const int wid = blockIdx.x;
  const int bx = (wid < 256) ? (wid >> 6) : (11 - (wid >> 6));
  const int bh = wid & 63;
  const int h = bh & 15, b = bh >> 4;
  const int i0 = bx * 128;
  const int r0 = i0 + wave * 32;
  const int nch = 2 * bx + 18;
  const int base = (i0 + 1023) & 2047;

  const u16* qB  = QH + (size_t)bh * (Ss * DKk);
  const u16* khB = KH + (size_t)bh * (Tt * DKk);
  const u16* vtB = VT + (size_t)bh * (DKk * Tt);
  const u16* rhB = RH + (size_t)h * (Tt * DKk);

  const float SC = 0.18033688011f;  // 0.125 * log2(e), folded into Q frags

  float ulo[8], uhi[8], vlo[8], vhi[8];
  {
    const float* up = ub + h * 64 + fq * 8;
    const float* vp = vbb + h * 64 + fq * 8;
    *(float4*)&ulo[0] = *(const float4*)up;
    *(float4*)&ulo[4] = *(const float4*)(up + 4);
    *(float4*)&uhi[0] = *(const float4*)(up + 32);
    *(float4*)&uhi[4] = *(const float4*)(up + 36);
    *(float4*)&vlo[0] = *(const float4*)vp;
    *(float4*)&vlo[4] = *(const float4*)(vp + 4);
    *(float4*)&vhi[0] = *(const float4*)(vp + 32);
    *(float4*)&vhi[4] = *(const float4*)(vp + 36);
  }

  s16x8 qu[2][2], qv[2][2];
#pragma unroll
  for (int s = 0; s < 2; ++s) {
    const u16* qp = qB + (size_t)(r0 + s * 16 + fr) * DKk + fq * 8;
    const s16x8 q0 = *(const s16x8*)qp;
    const s16x8 q1 = *(const s16x8*)(qp + 32);
    union U8 { s16x8 v; uint32_t w[4]; } a0, a1, c0, c1;
#pragma unroll
    for (int e = 0; e < 4; ++e) {
      a0.w[e] = pk2((b2f(q0[2*e]) + ulo[2*e]) * SC, (b2f(q0[2*e+1]) + ulo[2*e+1]) * SC);
      a1.w[e] = pk2((b2f(q1[2*e]) + uhi[2*e]) * SC, (b2f(q1[2*e+1]) + uhi[2*e+1]) * SC);
      c0.w[e] = pk2((b2f(q0[2*e]) + vlo[2*e]) * SC, (b2f(q0[2*e+1]) + vlo[2*e+1]) * SC);
      c1.w[e] = pk2((b2f(q1[2*e]) + vhi[2*e]) * SC, (b2f(q1[2*e+1]) + vhi[2*e+1]) * SC);
    }
    qu[s][0] = a0.v; qu[s][1] = a1.v; qv[s][0] = c0.v; qv[s][1] = c1.v;
  }

  s16x8 vone;
  {
    union U8 { s16x8 v; uint32_t w[4]; } o;
    const uint32_t f = (fr == 0) ? 0x3F803F80u : 0u;
#pragma unroll
    for (int e = 0; e < 4; ++e) o.w[e] = f;
    vone = o.v;
  }

  const int srow = lane >> 3, sch = lane & 7;
  const int row0 = wave * 8 + srow;
  const int row1 = wave * 8 + 32 + srow;
  const int swc = (sch ^ srow) * 8;

  f32x4 pacc[2][4];  // BD for the UPCOMING chunk (built at previous tail)

  auto computeBD = [&](int jw) {
    s16x8 rf[6][2];
#pragma unroll
    for (int mt = 0; mt < 6; ++mt) {
      const int rho = (jw + wave * 32 + mt * 16 + fr) & 255;
#pragma unroll
      for (int hh = 0; hh < 2; ++hh)
        rf[mt][hh] = *(const s16x8*)&RB[rho * 64 + (((hh * 4 + fq) ^ (rho & 7)) * 8)];
    }
#pragma unroll
    for (int s = 0; s < 2; ++s) {
      f32x4 g[5];
      __builtin_amdgcn_s_setprio(1);
#pragma unroll
      for (int k2 = 0; k2 < 5; ++k2) {
        f32x4 t = {};
        t = mfma16(qv[s][0], rf[s + k2][0], t);
        t = mfma16(qv[s][1], rf[s + k2][1], t);
        g[k2] = t;
      }
      __builtin_amdgcn_s_setprio(0);
#pragma unroll
      for (int r = 0; r < 4; ++r) {
        const int sum = fq * 4 + r + fr;
        const int src = fq * 16 + (sum & 15);
        const bool cy = sum >= 16;
        const float s0 = __shfl(g[0][r], src);
        const float s1 = __shfl(g[1][r], src);
        const float s2 = __shfl(g[2][r], src);
        const float s3 = __shfl(g[3][r], src);
        const float s4 = __shfl(g[4][r], src);
        pacc[s][0][r] = cy ? s1 : s0;
        pacc[s][1][r] = cy ? s2 : s1;
        pacc[s][2][r] = cy ? s3 : s2;
        pacc[s][3][r] = cy ? s4 : s3;
      }
    }
  };

  // prologue: RB ring FULL 256 rows (positions base+0..255), K/V chunk 0
#pragma unroll
  for (int p = 0; p < 8; ++p) {
    const int off = p * 32 + wave * 8 + srow;  // off&7 == srow
    const uint4 rr =
        *(const uint4*)(rhB + (size_t)((base + off) & 2047) * 64 + swc);
    *(uint4*)&RB[off * 64 + sch * 8] = rr;
  }
  {
    const uint4 k0 = *(const uint4*)(khB + (size_t)row0 * 64 + swc);
    const uint4 k1 = *(const uint4*)(khB + (size_t)row1 * 64 + swc);
    const uint4 v0 = *(const uint4*)(vtB + (size_t)row0 * Tt + swc);
    const uint4 v1 = *(const uint4*)(vtB + (size_t)row1 * Tt + swc);
    *(uint4*)&Ks[row0 * 64 + sch * 8] = k0;
    *(uint4*)&Ks[row1 * 64 + sch * 8] = k1;
    *(uint4*)&Vt[row0 * 64 + sch * 8] = v0;
    *(uint4*)&Vt[row1 * 64 + sch * 8] = v1;
  }
  __syncthreads();
  computeBD(0);

  f32x4 oacc[2][4] = {};
  f32x4 oacc2[2] = {};
  float mrun[2][4];
#pragma unroll
  for (int s = 0; s < 2; ++s)
#pragma unroll
    for (int r = 0; r < 4; ++r) mrun[s][r] = -1e30f;

  const float THR = 11.0f;  // defer-max threshold (log2 units)

  for (int c = 0; c < nch; ++c) {
    const int j0 = c * 64;
    const bool more = (c + 1 < nch);
    __syncthreads();

    uint4 kr0, kr1, vr0, vr1;
    if (more) {
      kr0 = *(const uint4*)(khB + (size_t)(j0 + 64 + row0) * 64 + swc);
      kr1 = *(const uint4*)(khB + (size_t)(j0 + 64 + row1) * 64 + swc);
      vr0 = *(const uint4*)(vtB + (size_t)row0 * Tt + (j0 + 64) + swc);
      vr1 = *(const uint4*)(vtB + (size_t)row1 * Tt + (j0 + 64) + swc);
    }

    // K fragments + AC accumulate into prebuilt BD (all pre-scaled)
    s16x8 kf[4][2];
#pragma unroll
    for (int ct = 0; ct < 4; ++ct) {
      const int row = ct * 16 + fr;
#pragma unroll
      for (int hh = 0; hh < 2; ++hh)
        kf[ct][hh] = *(const s16x8*)&Ks[row * 64 + (((hh * 4 + fq) ^ (row & 7)) * 8)];
    }
    __builtin_amdgcn_s_setprio(1);
#pragma unroll
    for (int s = 0; s < 2; ++s)
#pragma unroll
      for (int ct = 0; ct < 4; ++ct) {
        pacc[s][ct] = mfma16(qu[s][0], kf[ct][0], pacc[s][ct]);
        pacc[s][ct] = mfma16(qu[s][1], kf[ct][1], pacc[s][ct]);
      }
    __builtin_amdgcn_s_setprio(0);

    // mask (select only; scores pre-scaled) + deferred-max online softmax
#pragma unroll
    for (int s = 0; s < 2; ++s) {
      const int rbase = r0 + s * 16;
      if (j0 + 63 > rbase + MEMm) {
#pragma unroll
        for (int ct = 0; ct < 4; ++ct)
#pragma unroll
          for (int r = 0; r < 4; ++r) {
            const int gi = rbase + fq * 4 + r, gj = j0 + ct * 16 + fr;
            pacc[s][ct][r] = (gj > gi + MEMm) ? -1e30f : pacc[s][ct][r];
          }
      }
      float cm[4];
#pragma unroll
      for (int r = 0; r < 4; ++r) {
        float t = fmaxf(fmaxf(pacc[s][0][r], pacc[s][1][r]),
                        fmaxf(pacc[s][2][r], pacc[s][3][r]));
        int v = __builtin_bit_cast(int, t);
        int t2 = __builtin_amdgcn_update_dpp(v, v, 0xB1, 0xF, 0xF, true);
        t = fmaxf(t, __builtin_bit_cast(float, t2)); v = __builtin_bit_cast(int, t);
        t2 = __builtin_amdgcn_update_dpp(v, v, 0x4E, 0xF, 0xF, true);
        t = fmaxf(t, __builtin_bit_cast(float, t2)); v = __builtin_bit_cast(int, t);
        t2 = __builtin_amdgcn_update_dpp(v, v, 0x141, 0xF, 0xF, true);
        t = fmaxf(t, __builtin_bit_cast(float, t2)); v = __builtin_bit_cast(int, t);
        t2 = __builtin_amdgcn_update_dpp(v, v, 0x140, 0xF, 0xF, true);
        t = fmaxf(t, __builtin_bit_cast(float, t2));
        cm[r] = t;
      }
      bool need = false;
#pragma unroll
      for (int r = 0; r < 4; ++r) need = need || (cm[r] > mrun[s][r] + THR);
      if (__any(need)) {
        float alpha[4];
#pragma unroll
        for (int r = 0; r < 4; ++r) {
          const float mn = fmaxf(mrun[s][r], cm[r]);
          alpha[r] = exp2f(mrun[s][r] - mn);
          mrun[s][r] = mn;
        }
#pragma unroll
        for (int t = 0; t < 4; ++t)
#pragma unroll
          for (int r = 0; r < 4; ++r) oacc[s][t][r] *= alpha[r];
#pragma unroll
        for (int r = 0; r < 4; ++r) oacc2[s][r] *= alpha[r];
      }
#pragma unroll
      for (int ct = 0; ct < 4; ++ct)
#pragma unroll
        for (int r = 0; r < 4; ++r)
          pacc[s][ct][r] = exp2f(pacc[s][ct][r] - mrun[s][r]);
    }

    // next-window R ring loads: positions j0+256..j0+319 -> rows (j0..63)&255
    const int offA0 = j0 + 256 + wave * 8 + srow;  // &7 == srow
    const int offA1 = offA0 + 32;
    const uint4 rr0 =
        *(const uint4*)(rhB + (size_t)((base + offA0) & 2047) * 64 + swc);
    const uint4 rr1 =
        *(const uint4*)(rhB + (size_t)((base + offA1) & 2047) * 64 + swc);

    // P -> LDS (bf16) both sets, then A-fragments
#pragma unroll
    for (int s = 0; s < 2; ++s)
#pragma unroll
      for (int ct = 0; ct < 4; ++ct)
#pragma unroll
        for (int r = 0; r < 4; ++r)
          Pl[wave][s][(fq * 4 + r) * 72 + ct * 16 + fr] = f2bf(pacc[s][ct][r]);
    asm volatile("s_waitcnt lgkmcnt(0)" ::: "memory");
    __builtin_amdgcn_sched_barrier(0);
    s16x8 ap[2][2];
#pragma unroll
    for (int s = 0; s < 2; ++s)
#pragma unroll
      for (int hh = 0; hh < 2; ++hh)
        ap[s][hh] = *(const s16x8*)&Pl[wave][s][fr * 72 + hh * 32 + fq * 8];

    // V fragments + PV + denominator
    s16x8 vf[4][2];
#pragma unroll
    for (int nt = 0; nt < 4; ++nt) {
      const int row = nt * 16 + fr;
#pragma unroll
      for (int hh = 0; hh < 2; ++hh)
        vf[nt][hh] = *(const s16x8*)&Vt[row * 64 + (((hh * 4 + fq) ^ (row & 7)) * 8)];
    }
    __builtin_amdgcn_s_setprio(1);
#pragma unroll
    for (int s = 0; s < 2; ++s) {
#pragma unroll
      for (int nt = 0; nt < 4; ++nt) {
        oacc[s][nt] = mfma16(ap[s][0], vf[nt][0], oacc[s][nt]);
        oacc[s][nt] = mfma16(ap[s][1], vf[nt][1], oacc[s][nt]);
      }
      oacc2[s] = mfma16(ap[s][0], vone, oacc2[s]);
      oacc2[s] = mfma16(ap[s][1], vone, oacc2[s]);
    }
    __builtin_amdgcn_s_setprio(0);

    __syncthreads();
    if (more) {
      *(uint4*)&Ks[row0 * 64 + sch * 8] = kr0;
      *(uint4*)&Ks[row1 * 64 + sch * 8] = kr1;
      *(uint4*)&Vt[row0 * 64 + sch * 8] = vr0;
      *(uint4*)&Vt[row1 * 64 + sch * 8] = vr1;
    }
    // write rows (j0..j0+63)&255 — complement of the tail read window below
    *(uint4*)&RB[(offA0 & 255) * 64 + sch * 8] = rr0;
    *(uint4*)&RB[(offA1 & 255) * 64 + sch * 8] = rr1;

    // tail: BD for chunk c+1 reads rows (j0+64..j0+255)&255 — disjoint
    if (more) computeBD(j0 + 64);
  }

  // epilogue
#pragma unroll
  for (int s = 0; s < 2; ++s) {
    float linv[4];
#pragma unroll
    for (int r = 0; r < 4; ++r)
      linv[r] = 1.0f / __shfl(oacc2[s][r], lane & 48);
#pragma unroll
    for (int nt = 0; nt < 4; ++nt)
#pragma unroll
      for (int r = 0; r < 4; ++r) {
        const int gi = r0 + s * 16 + fq * 4 + r;
        CONCAT[((size_t)b * Ss + gi) * Dd + h * DKk + nt * 16 + fr] =
            f2bf(oacc[s][nt][r] * linv[r]);
      }
  }
}

// ---------------------------------------------------------------------------
extern "C" void kernel_launch(void* const* d_in, const int* in_sizes, int n_in,
                              void* d_out, int out_size, void* d_ws,
                              size_t ws_size, hipStream_t stream) {
  (void)in_sizes; (void)n_in; (void)out_size; (void)ws_size;
  const float* q  = (const float*)d_in[0];
  const float* k  = (const float*)d_in[1];
  const float* v  = (const float*)d_in[2];
  // d_in[3] = mask: analytic (j <= i + MEM), unused
  const float* u  = (const float*)d_in[4];
  const float* vb = (const float*)d_in[5];
  const float* Wq = (const float*)d_in[6];
  const float* Wk = (const float*)d_in[7];
  const float* Wv = (const float*)d_in[8];
  const float* Wr = (const float*)d_in[9];
  const float* Wo = (const float*)d_in[10];
  const float* R  = (const float*)d_in[11];

  char* ws = (char*)d_ws;
  u16* QH  = (u16*)ws; ws += 8388608;    // [B,H,S,DK] bf16          (8 MB)
  u16* KH  = (u16*)ws; ws += 16777216;   // [B,H,T,DK]               (16 MB)
  u16* VT  = (u16*)ws; ws += 16777216;   // [B,H,DK,T]               (16 MB)
  u16* RH  = (u16*)ws; ws += 4194304;    // [H,T,DK]                 (4 MB)
  u16* Wb  = (u16*)ws; ws += 10485760;   // 5 x 1M bf16 weights      (10 MB)
  u16* CONCAT = (u16*)ws;                // 8 MB

  const size_t M1 = (size_t)1 << 20;

  cvt5w<<<dim3(512, 5), 256, 0, stream>>>(Wq, Wk, Wv, Wr, Wo, Wb);
  gemm_all<<<1408, 256, 0, stream>>>(k, v, q, R, Wb, QH, KH, VT, RH);
  attn14<<<512, 256, 0, stream>>>(QH, KH, VT, RH, u, vb, CONCAT);
  gemm_o<<<512, 256, 0, stream>>>(CONCAT, Wb + 4 * M1, (float*)d_out);
}

// Round 23
// 212.302 us; speedup vs baseline: 1.0066x; 1.0066x over previous
//
#include <hip/hip_runtime.h>
#include <hip/hip_bf16.h>
#include <stdint.h>

#define Ss   1024
#define MEMm 1024
#define Tt   2048
#define Dd   1024
#define Hh   16
#define DKk  64

typedef unsigned short u16;
using f32x4 = __attribute__((ext_vector_type(4))) float;
using s16x8 = __attribute__((ext_vector_type(8))) short;

__device__ __forceinline__ u16 f2bf(float x) {
  __hip_bfloat16 h = __float2bfloat16(x);
  return *(reinterpret_cast<u16*>(&h));
}
__device__ __forceinline__ float b2f(short s) {
  union { uint32_t u; float f; } c; c.u = ((uint32_t)(u16)s) << 16; return c.f;
}
__device__ __forceinline__ uint32_t pk2(float lo, float hi) {
  return (uint32_t)f2bf(lo) | ((uint32_t)f2bf(hi) << 16);
}
__device__ __forceinline__ f32x4 mfma16(s16x8 a, s16x8 b, f32x4 c) {
  return __builtin_amdgcn_mfma_f32_16x16x32_bf16(a, b, c, 0, 0, 0);
}
__device__ __forceinline__ void gl_lds16(const u16* g, u16* l) {
  __builtin_amdgcn_global_load_lds(
      (const __attribute__((address_space(1))) uint32_t*)g,
      (__attribute__((address_space(3))) uint32_t*)l, 16, 0, 0);
}

// ---------------------------------------------------------------------------
// Weight conversion only (activations consumed as f32 directly by gemm_all).
// ---------------------------------------------------------------------------
__global__ __launch_bounds__(256)
void cvt5w(const float* __restrict__ w0, const float* __restrict__ w1,
           const float* __restrict__ w2, const float* __restrict__ w3,
           const float* __restrict__ w4, u16* __restrict__ Wb) {
  const float* s;
  switch (blockIdx.y) {
    case 0: s = w0; break; case 1: s = w1; break; case 2: s = w2; break;
    case 3: s = w3; break; default: s = w4; break;
  }
  const int idx = blockIdx.x * 256 + threadIdx.x;
  const float4* p = (const float4*)(s + (size_t)idx * 8);
  const float4 a = p[0], bq = p[1];
  uint4 o;
  o.x = pk2(a.x, a.y);   o.y = pk2(a.z, a.w);
  o.z = pk2(bq.x, bq.y); o.w = pk2(bq.z, bq.w);
  *(uint4*)(Wb + ((size_t)blockIdx.y << 20) + (size_t)idx * 8) = o;
}

// ---------------------------------------------------------------------------
// Shared GEMM epilogue.  EPI: 0=QH, 1=KH, 2=VT(transposed), 3=RH, 4=fp32 out
// ---------------------------------------------------------------------------
template <int EPI>
__device__ __forceinline__
void gemm_epi(f32x4 (&acc)[4][4], void* __restrict__ O, int n0, int m0) {
  const int lane = threadIdx.x & 63, wave = threadIdx.x >> 6;
  const int fr = lane & 15, fq = lane >> 4;
  const int wr = (wave >> 1) * 64, wc = (wave & 1) * 64;
#pragma unroll
  for (int i = 0; i < 4; ++i)
#pragma unroll
    for (int j = 0; j < 4; ++j) {
      if constexpr (EPI == 2) {
        const int grow = n0 + wr + i * 16 + fq * 4;
        const int m = m0 + wc + j * 16 + fr;
        const int bb = grow >> 11, t = grow & 2047;
        const int hh = m >> 6, dk = m & 63;
        ushort4 pk4;
        pk4.x = f2bf(acc[i][j][0]); pk4.y = f2bf(acc[i][j][1]);
        pk4.z = f2bf(acc[i][j][2]); pk4.w = f2bf(acc[i][j][3]);
        *(ushort4*)&((u16*)O)[(((size_t)(bb * Hh + hh) * DKk + dk) << 11) + t] = pk4;
      } else {
#pragma unroll
        for (int r = 0; r < 4; ++r) {
          const int n = n0 + wr + i * 16 + fq * 4 + r;
          const int m = m0 + wc + j * 16 + fr;
          const float y = acc[i][j][r];
          if constexpr (EPI == 0) {
            const int bb = n >> 10, s = n & 1023, hh = m >> 6, dk = m & 63;
            ((u16*)O)[((size_t)(bb * Hh + hh) * Ss + s) * DKk + dk] = f2bf(y);
          } else if constexpr (EPI == 1) {
            const int bb = n >> 11, t = n & 2047, hh = m >> 6, dk = m & 63;
            ((u16*)O)[((size_t)(bb * Hh + hh) * Tt + t) * DKk + dk] = f2bf(y);
          } else if constexpr (EPI == 3) {
            const int hh = m >> 6, dk = m & 63;
            ((u16*)O)[((size_t)hh * Tt + n) * DKk + dk] = f2bf(y);
          } else {
            ((float*)O)[(size_t)n * Dd + m] = y;
          }
        }
      }
    }
}

// ---------------------------------------------------------------------------
// fp32-A body, BK=64 (round-19 proven): A 8x float4 global loads issued
// first; 4 contiguous ds_write_b128 (conflict-free), parity XOR on write &
// read. B: 4 pre-swizzled gl_lds (bf16 weights).
// ---------------------------------------------------------------------------
template <int EPI>
__device__ __forceinline__
void gemm_body_f32(const float* __restrict__ X, const u16* __restrict__ W,
                   void* __restrict__ O, int n0, int m0, u16* As, u16* Bs) {
  const int tid = threadIdx.x;
  const int lane = tid & 63, wave = tid >> 6;
  const int fr = lane & 15, fq = lane >> 4;
  const int wr = (wave >> 1) * 64, wc = (wave & 1) * 64;
  f32x4 acc[4][4] = {};

  const int arow8 = tid >> 3;        // 0..31
  const int aseg  = tid & 7;         // 0..7
  const int lrow8 = lane >> 3;       // 0..7 (B staging)
  const int lcol  = (lane & 7) * 8;

  for (int k0 = 0; k0 < Dd; k0 += 64) {
    // issue all A loads (global f32; no LDS dependency)
    float4 fa[4][2];
#pragma unroll
    for (int p = 0; p < 4; ++p) {
      const float* src = X + (size_t)(n0 + p * 32 + arow8) * Dd + k0 + aseg * 8;
      fa[p][0] = *(const float4*)src;
      fa[p][1] = *(const float4*)(src + 4);
    }
    // B staging via gl_lds
#pragma unroll
    for (int p = 0; p < 4; ++p) {
      const int row = p * 32 + wave * 8 + lrow8;
      const int scol = lcol ^ ((row & 1) * 32);
      gl_lds16(W + (size_t)(m0 + row) * Dd + k0 + scol,
               &Bs[(p * 32 + wave * 8) * 64]);
    }
    // A cvt + conflict-free ds_write (parity XOR, matches read side)
#pragma unroll
    for (int p = 0; p < 4; ++p) {
      const int row = p * 32 + arow8;
      uint4 pk4;
      pk4.x = pk2(fa[p][0].x, fa[p][0].y);
      pk4.y = pk2(fa[p][0].z, fa[p][0].w);
      pk4.z = pk2(fa[p][1].x, fa[p][1].y);
      pk4.w = pk2(fa[p][1].z, fa[p][1].w);
      *(uint4*)&As[row * 64 + ((aseg * 8) ^ ((row & 1) * 32))] = pk4;
    }
    __syncthreads();  // staging visible (drains vmcnt incl. gl_lds)
#pragma unroll
    for (int kc = 0; kc < 2; ++kc) {
      s16x8 af[4], bfv[4];
#pragma unroll
      for (int i = 0; i < 4; ++i) {
        const int row = wr + i * 16 + fr;
        af[i] = *(const s16x8*)&As[row * 64 + ((kc * 32 + fq * 8) ^ ((row & 1) * 32))];
      }
#pragma unroll
      for (int j = 0; j < 4; ++j) {
        const int row = wc + j * 16 + fr;
        bfv[j] = *(const s16x8*)&Bs[row * 64 + ((kc * 32 + fq * 8) ^ ((row & 1) * 32))];
      }
#pragma unroll
      for (int i = 0; i < 4; ++i)
#pragma unroll
        for (int j = 0; j < 4; ++j)
          acc[i][j] = mfma16(af[i], bfv[j], acc[i][j]);
    }
    __syncthreads();  // reads done before next iteration's staging
  }
  gemm_epi<EPI>(acc, O, n0, m0);
}

// ---------------------------------------------------------------------------
// All four projections in ONE dispatch (1408 blocks), f32-A BK=64 path,
// XCD-bijective swizzle (1408 = 8 x 176).
// ---------------------------------------------------------------------------
__global__ __launch_bounds__(256, 2)
void gemm_all(const float* __restrict__ kf, const float* __restrict__ vf,
              const float* __restrict__ qf, const float* __restrict__ Rf,
              const u16* __restrict__ Wb,
              u16* __restrict__ QH, u16* __restrict__ KH,
              u16* __restrict__ VT, u16* __restrict__ RH) {
  __shared__ u16 As[128 * 64];
  __shared__ u16 Bs[128 * 64];
  const int bid = (blockIdx.x & 7) * 176 + (blockIdx.x >> 3);  // XCD swizzle
  if (bid < 512) {
    const int t = bid;
    gemm_body_f32<1>(kf, Wb + ((size_t)1 << 20), KH,
                     (t >> 3) * 128, (t & 7) * 128, As, Bs);
  } else if (bid < 1024) {
    const int t = bid - 512;
    gemm_body_f32<2>(vf, Wb + ((size_t)2 << 20), VT,
                     (t >> 3) * 128, (t & 7) * 128, As, Bs);
  } else if (bid < 1280) {
    const int t = bid - 1024;
    gemm_body_f32<0>(qf, Wb, QH, (t >> 3) * 128, (t & 7) * 128, As, Bs);
  } else {
    const int t = bid - 1280;
    gemm_body_f32<3>(Rf, Wb + ((size_t)3 << 20), RH,
                     (t >> 3) * 128, (t & 7) * 128, As, Bs);
  }
}

// ---------------------------------------------------------------------------
// o-projection (fp32 out), 128x64 tiles -> 512 blocks = 2 blocks/CU.
// BK=64 + parity XOR swizzle, acc[4][2]. XCD swizzle 512 = 8 x 64.
// ---------------------------------------------------------------------------
__global__ __launch_bounds__(256, 2)
void gemm_o(const u16* __restrict__ X, const u16* __restrict__ W,
            float* __restrict__ O) {
  __shared__ u16 As[128 * 64];
  __shared__ u16 Bs[64 * 64];
  const int t = (blockIdx.x & 7) * 64 + (blockIdx.x >> 3);  // XCD swizzle
  const int n0 = (t >> 4) * 128;   // 32 n-tiles
  const int m0 = (t & 15) * 64;    // 16 m-tiles
  const int tid = threadIdx.x;
  const int lane = tid & 63, wave = tid >> 6;
  const int fr = lane & 15, fq = lane >> 4;
  const int wr = (wave >> 1) * 64, wc = (wave & 1) * 32;
  f32x4 acc[4][2] = {};

  const int lrow8 = lane >> 3;
  const int lcol  = (lane & 7) * 8;

  for (int k0 = 0; k0 < Dd; k0 += 64) {
#pragma unroll
    for (int p = 0; p < 4; ++p) {
      const int row = p * 32 + wave * 8 + lrow8;
      const int scol = lcol ^ ((row & 1) * 32);
      gl_lds16(X + (size_t)(n0 + row) * Dd + k0 + scol, &As[(p * 32 + wave * 8) * 64]);
    }
#pragma unroll
    for (int p = 0; p < 2; ++p) {
      const int row = p * 32 + wave * 8 + lrow8;
      const int scol = lcol ^ ((row & 1) * 32);
      gl_lds16(W + (size_t)(m0 + row) * Dd + k0 + scol, &Bs[(p * 32 + wave * 8) * 64]);
    }
    __syncthreads();
#pragma unroll
    for (int kc = 0; kc < 2; ++kc) {
      s16x8 af[4], bfv[2];
#pragma unroll
      for (int i = 0; i < 4; ++i) {
        const int row = wr + i * 16 + fr;
        af[i] = *(const s16x8*)&As[row * 64 + ((kc * 32 + fq * 8) ^ ((row & 1) * 32))];
      }
#pragma unroll
      for (int j = 0; j < 2; ++j) {
        const int row = wc + j * 16 + fr;
        bfv[j] = *(const s16x8*)&Bs[row * 64 + ((kc * 32 + fq * 8) ^ ((row & 1) * 32))];
      }
#pragma unroll
      for (int i = 0; i < 4; ++i)
#pragma unroll
        for (int j = 0; j < 2; ++j)
          acc[i][j] = mfma16(af[i], bfv[j], acc[i][j]);
    }
    __syncthreads();
  }

#pragma unroll
  for (int i = 0; i < 4; ++i)
#pragma unroll
    for (int j = 0; j < 2; ++j)
#pragma unroll
      for (int r = 0; r < 4; ++r) {
        const int n = n0 + wr + i * 16 + fq * 4 + r;
        const int m = m0 + wc + j * 16 + fr;
        O[(size_t)n * Dd + m] = acc[i][j][r];
      }
}

// ---------------------------------------------------------------------------
// Fused TXL attention v14 (proven: ring-race-free BD-at-tail pipelining,
// SC folded into Q frags, defer-max, (256,2) VGPR cap).
// Byte-identical to rounds 16-21.
// ---------------------------------------------------------------------------
__global__ __launch_bounds__(256, 2)
void attn14(const u16* __restrict__ QH, const u16* __restrict__ KH,
            const u16* __restrict__ VT, const u16* __restrict__ RH,
            const float* __restrict__ ub, const float* __restrict__ vbb,
            u16* __restrict__ CONCAT) {
  __shared__ u16 Ks[64 * 64];
  __shared__ u16 Vt[64 * 64];
  __shared__ u16 RB[256 * 64];
  __shared__ u16 Pl[4][2][16 * 72];

  const int tid = threadIdx.x;
  const int wave = tid >> 6, lane = tid & 63;
  const int fr = lane & 15, fq = lane >> 4;

  const int wid = blockIdx.x;
  const int bx = (wid < 256) ? (wid >> 6) : (11 - (wid >> 6));
  const int bh = wid & 63;
  const int h = bh & 15, b = bh >> 4;
  const int i0 = bx * 128;
  const int r0 = i0 + wave * 32;
  const int nch = 2 * bx + 18;
  const int base = (i0 + 1023) & 2047;

  const u16* qB  = QH + (size_t)bh * (Ss * DKk);
  const u16* khB = KH + (size_t)bh * (Tt * DKk);
  const u16* vtB = VT + (size_t)bh * (DKk * Tt);
  const u16* rhB = RH + (size_t)h * (Tt * DKk);

  const float SC = 0.18033688011f;  // 0.125 * log2(e), folded into Q frags

  float ulo[8], uhi[8], vlo[8], vhi[8];
  {
    const float* up = ub + h * 64 + fq * 8;
    const float* vp = vbb + h * 64 + fq * 8;
    *(float4*)&ulo[0] = *(const float4*)up;
    *(float4*)&ulo[4] = *(const float4*)(up + 4);
    *(float4*)&uhi[0] = *(const float4*)(up + 32);
    *(float4*)&uhi[4] = *(const float4*)(up + 36);
    *(float4*)&vlo[0] = *(const float4*)vp;
    *(float4*)&vlo[4] = *(const float4*)(vp + 4);
    *(float4*)&vhi[0] = *(const float4*)(vp + 32);
    *(float4*)&vhi[4] = *(const float4*)(vp + 36);
  }

  s16x8 qu[2][2], qv[2][2];
#pragma unroll
  for (int s = 0; s < 2; ++s) {
    const u16* qp = qB + (size_t)(r0 + s * 16 + fr) * DKk + fq * 8;
    const s16x8 q0 = *(const s16x8*)qp;
    const s16x8 q1 = *(const s16x8*)(qp + 32);
    union U8 { s16x8 v; uint32_t w[4]; } a0, a1, c0, c1;
#pragma unroll
    for (int e = 0; e < 4; ++e) {
      a0.w[e] = pk2((b2f(q0[2*e]) + ulo[2*e]) * SC, (b2f(q0[2*e+1]) + ulo[2*e+1]) * SC);
      a1.w[e] = pk2((b2f(q1[2*e]) + uhi[2*e]) * SC, (b2f(q1[2*e+1]) + uhi[2*e+1]) * SC);
      c0.w[e] = pk2((b2f(q0[2*e]) + vlo[2*e]) * SC, (b2f(q0[2*e+1]) + vlo[2*e+1]) * SC);
      c1.w[e] = pk2((b2f(q1[2*e]) + vhi[2*e]) * SC, (b2f(q1[2*e+1]) + vhi[2*e+1]) * SC);
    }
    qu[s][0] = a0.v; qu[s][1] = a1.v; qv[s][0] = c0.v; qv[s][1] = c1.v;
  }

  s16x8 vone;
  {
    union U8 { s16x8 v; uint32_t w[4]; } o;
    const uint32_t f = (fr == 0) ? 0x3F803F80u : 0u;
#pragma unroll
    for (int e = 0; e < 4; ++e) o.w[e] = f;
    vone = o.v;
  }

  const int srow = lane >> 3, sch = lane & 7;
  const int row0 = wave * 8 + srow;
  const int row1 = wave * 8 + 32 + srow;
  const int swc = (sch ^ srow) * 8;

  f32x4 pacc[2][4];  // BD for the UPCOMING chunk (built at previous tail)

  auto computeBD = [&](int jw) {
    s16x8 rf[6][2];
#pragma unroll
    for (int mt = 0; mt < 6; ++mt) {
      const int rho = (jw + wave * 32 + mt * 16 + fr) & 255;
#pragma unroll
      for (int hh = 0; hh < 2; ++hh)
        rf[mt][hh] = *(const s16x8*)&RB[rho * 64 + (((hh * 4 + fq) ^ (rho & 7)) * 8)];
    }
#pragma unroll
    for (int s = 0; s < 2; ++s) {
      f32x4 g[5];
      __builtin_amdgcn_s_setprio(1);
#pragma unroll
      for (int k2 = 0; k2 < 5; ++k2) {
        f32x4 t = {};
        t = mfma16(qv[s][0], rf[s + k2][0], t);
        t = mfma16(qv[s][1], rf[s + k2][1], t);
        g[k2] = t;
      }
      __builtin_amdgcn_s_setprio(0);
#pragma unroll
      for (int r = 0; r < 4; ++r) {
        const int sum = fq * 4 + r + fr;
        const int src = fq * 16 + (sum & 15);
        const bool cy = sum >= 16;
        const float s0 = __shfl(g[0][r], src);
        const float s1 = __shfl(g[1][r], src);
        const float s2 = __shfl(g[2][r], src);
        const float s3 = __shfl(g[3][r], src);
        const float s4 = __shfl(g[4][r], src);
        pacc[s][0][r] = cy ? s1 : s0;
        pacc[s][1][r] = cy ? s2 : s1;
        pacc[s][2][r] = cy ? s3 : s2;
        pacc[s][3][r] = cy ? s4 : s3;
      }
    }
  };

  // prologue: RB ring FULL 256 rows (positions base+0..255), K/V chunk 0
#pragma unroll
  for (int p = 0; p < 8; ++p) {
    const int off = p * 32 + wave * 8 + srow;  // off&7 == srow
    const uint4 rr =
        *(const uint4*)(rhB + (size_t)((base + off) & 2047) * 64 + swc);
    *(uint4*)&RB[off * 64 + sch * 8] = rr;
  }
  {
    const uint4 k0 = *(const uint4*)(khB + (size_t)row0 * 64 + swc);
    const uint4 k1 = *(const uint4*)(khB + (size_t)row1 * 64 + swc);
    const uint4 v0 = *(const uint4*)(vtB + (size_t)row0 * Tt + swc);
    const uint4 v1 = *(const uint4*)(vtB + (size_t)row1 * Tt + swc);
    *(uint4*)&Ks[row0 * 64 + sch * 8] = k0;
    *(uint4*)&Ks[row1 * 64 + sch * 8] = k1;
    *(uint4*)&Vt[row0 * 64 + sch * 8] = v0;
    *(uint4*)&Vt[row1 * 64 + sch * 8] = v1;
  }
  __syncthreads();
  computeBD(0);

  f32x4 oacc[2][4] = {};
  f32x4 oacc2[2] = {};
  float mrun[2][4];
#pragma unroll
  for (int s = 0; s < 2; ++s)
#pragma unroll
    for (int r = 0; r < 4; ++r) mrun[s][r] = -1e30f;

  const float THR = 11.0f;  // defer-max threshold (log2 units)

  for (int c = 0; c < nch; ++c) {
    const int j0 = c * 64;
    const bool more = (c + 1 < nch);
    __syncthreads();

    uint4 kr0, kr1, vr0, vr1;
    if (more) {
      kr0 = *(const uint4*)(khB + (size_t)(j0 + 64 + row0) * 64 + swc);
      kr1 = *(const uint4*)(khB + (size_t)(j0 + 64 + row1) * 64 + swc);
      vr0 = *(const uint4*)(vtB + (size_t)row0 * Tt + (j0 + 64) + swc);
      vr1 = *(const uint4*)(vtB + (size_t)row1 * Tt + (j0 + 64) + swc);
    }

    // K fragments + AC accumulate into prebuilt BD (all pre-scaled)
    s16x8 kf[4][2];
#pragma unroll
    for (int ct = 0; ct < 4; ++ct) {
      const int row = ct * 16 + fr;
#pragma unroll
      for (int hh = 0; hh < 2; ++hh)
        kf[ct][hh] = *(const s16x8*)&Ks[row * 64 + (((hh * 4 + fq) ^ (row & 7)) * 8)];
    }
    __builtin_amdgcn_s_setprio(1);
#pragma unroll
    for (int s = 0; s < 2; ++s)
#pragma unroll
      for (int ct = 0; ct < 4; ++ct) {
        pacc[s][ct] = mfma16(qu[s][0], kf[ct][0], pacc[s][ct]);
        pacc[s][ct] = mfma16(qu[s][1], kf[ct][1], pacc[s][ct]);
      }
    __builtin_amdgcn_s_setprio(0);

    // mask (select only; scores pre-scaled) + deferred-max online softmax
#pragma unroll
    for (int s = 0; s < 2; ++s) {
      const int rbase = r0 + s * 16;
      if (j0 + 63 > rbase + MEMm) {
#pragma unroll
        for (int ct = 0; ct < 4; ++ct)
#pragma unroll
          for (int r = 0; r < 4; ++r) {
            const int gi = rbase + fq * 4 + r, gj = j0 + ct * 16 + fr;
            pacc[s][ct][r] = (gj > gi + MEMm) ? -1e30f : pacc[s][ct][r];
          }
      }
      float cm[4];
#pragma unroll
      for (int r = 0; r < 4; ++r) {
        float t = fmaxf(fmaxf(pacc[s][0][r], pacc[s][1][r]),
                        fmaxf(pacc[s][2][r], pacc[s][3][r]));
        int v = __builtin_bit_cast(int, t);
        int t2 = __builtin_amdgcn_update_dpp(v, v, 0xB1, 0xF, 0xF, true);
        t = fmaxf(t, __builtin_bit_cast(float, t2)); v = __builtin_bit_cast(int, t);
        t2 = __builtin_amdgcn_update_dpp(v, v, 0x4E, 0xF, 0xF, true);
        t = fmaxf(t, __builtin_bit_cast(float, t2)); v = __builtin_bit_cast(int, t);
        t2 = __builtin_amdgcn_update_dpp(v, v, 0x141, 0xF, 0xF, true);
        t = fmaxf(t, __builtin_bit_cast(float, t2)); v = __builtin_bit_cast(int, t);
        t2 = __builtin_amdgcn_update_dpp(v, v, 0x140, 0xF, 0xF, true);
        t = fmaxf(t, __builtin_bit_cast(float, t2));
        cm[r] = t;
      }
      bool need = false;
#pragma unroll
      for (int r = 0; r < 4; ++r) need = need || (cm[r] > mrun[s][r] + THR);
      if (__any(need)) {
        float alpha[4];
#pragma unroll
        for (int r = 0; r < 4; ++r) {
          const float mn = fmaxf(mrun[s][r], cm[r]);
          alpha[r] = exp2f(mrun[s][r] - mn);
          mrun[s][r] = mn;
        }
#pragma unroll
        for (int t = 0; t < 4; ++t)
#pragma unroll
          for (int r = 0; r < 4; ++r) oacc[s][t][r] *= alpha[r];
#pragma unroll
        for (int r = 0; r < 4; ++r) oacc2[s][r] *= alpha[r];
      }
#pragma unroll
      for (int ct = 0; ct < 4; ++ct)
#pragma unroll
        for (int r = 0; r < 4; ++r)
          pacc[s][ct][r] = exp2f(pacc[s][ct][r] - mrun[s][r]);
    }

    // next-window R ring loads: positions j0+256..j0+319 -> rows (j0..63)&255
    const int offA0 = j0 + 256 + wave * 8 + srow;  // &7 == srow
    const int offA1 = offA0 + 32;
    const uint4 rr0 =
        *(const uint4*)(rhB + (size_t)((base + offA0) & 2047) * 64 + swc);
    const uint4 rr1 =
        *(const uint4*)(rhB + (size_t)((base + offA1) & 2047) * 64 + swc);

    // P -> LDS (bf16) both sets, then A-fragments
#pragma unroll
    for (int s = 0; s < 2; ++s)
#pragma unroll
      for (int ct = 0; ct < 4; ++ct)
#pragma unroll
        for (int r = 0; r < 4; ++r)
          Pl[wave][s][(fq * 4 + r) * 72 + ct * 16 + fr] = f2bf(pacc[s][ct][r]);
    asm volatile("s_waitcnt lgkmcnt(0)" ::: "memory");
    __builtin_amdgcn_sched_barrier(0);
    s16x8 ap[2][2];
#pragma unroll
    for (int s = 0; s < 2; ++s)
#pragma unroll
      for (int hh = 0; hh < 2; ++hh)
        ap[s][hh] = *(const s16x8*)&Pl[wave][s][fr * 72 + hh * 32 + fq * 8];

    // V fragments + PV + denominator
    s16x8 vf[4][2];
#pragma unroll
    for (int nt = 0; nt < 4; ++nt) {
      const int row = nt * 16 + fr;
#pragma unroll
      for (int hh = 0; hh < 2; ++hh)
        vf[nt][hh] = *(const s16x8*)&Vt[row * 64 + (((hh * 4 + fq) ^ (row & 7)) * 8)];
    }
    __builtin_amdgcn_s_setprio(1);
#pragma unroll
    for (int s = 0; s < 2; ++s) {
#pragma unroll
      for (int nt = 0; nt < 4; ++nt) {
        oacc[s][nt] = mfma16(ap[s][0], vf[nt][0], oacc[s][nt]);
        oacc[s][nt] = mfma16(ap[s][1], vf[nt][1], oacc[s][nt]);
      }
      oacc2[s] = mfma16(ap[s][0], vone, oacc2[s]);
      oacc2[s] = mfma16(ap[s][1], vone, oacc2[s]);
    }
    __builtin_amdgcn_s_setprio(0);

    __syncthreads();
    if (more) {
      *(uint4*)&Ks[row0 * 64 + sch * 8] = kr0;
      *(uint4*)&Ks[row1 * 64 + sch * 8] = kr1;
      *(uint4*)&Vt[row0 * 64 + sch * 8] = vr0;
      *(uint4*)&Vt[row1 * 64 + sch * 8] = vr1;
    }
    // write rows (j0..j0+63)&255 — complement of the tail read window below
    *(uint4*)&RB[(offA0 & 255) * 64 + sch * 8] = rr0;
    *(uint4*)&RB[(offA1 & 255) * 64 + sch * 8] = rr1;

    // tail: BD for chunk c+1 reads rows (j0+64..j0+255)&255 — disjoint
    if (more) computeBD(j0 + 64);
  }

  // epilogue
#pragma unroll
  for (int s = 0; s < 2; ++s) {
    float linv[4];
#pragma unroll
    for (int r = 0; r < 4; ++r)
      linv[r] = 1.0f / __shfl(oacc2[s][r], lane & 48);
#pragma unroll
    for (int nt = 0; nt < 4; ++nt)
#pragma unroll
      for (int r = 0; r < 4; ++r) {
        const int gi = r0 + s * 16 + fq * 4 + r;
        CONCAT[((size_t)b * Ss + gi) * Dd + h * DKk + nt * 16 + fr] =
            f2bf(oacc[s][nt][r] * linv[r]);
      }
  }
}

// ---------------------------------------------------------------------------
extern "C" void kernel_launch(void* const* d_in, const int* in_sizes, int n_in,
                              void* d_out, int out_size, void* d_ws,
                              size_t ws_size, hipStream_t stream) {
  (void)in_sizes; (void)n_in; (void)out_size; (void)ws_size;
  const float* q  = (const float*)d_in[0];
  const float* k  = (const float*)d_in[1];
  const float* v  = (const float*)d_in[2];
  // d_in[3] = mask: analytic (j <= i + MEM), unused
  const float* u  = (const float*)d_in[4];
  const float* vb = (const float*)d_in[5];
  const float* Wq = (const float*)d_in[6];
  const float* Wk = (const float*)d_in[7];
  const float* Wv = (const float*)d_in[8];
  const float* Wr = (const float*)d_in[9];
  const float* Wo = (const float*)d_in[10];
  const float* R  = (const float*)d_in[11];

  char* ws = (char*)d_ws;
  u16* QH  = (u16*)ws; ws += 8388608;    // [B,H,S,DK] bf16          (8 MB)
  u16* KH  = (u16*)ws; ws += 16777216;   // [B,H,T,DK]               (16 MB)
  u16* VT  = (u16*)ws; ws += 16777216;   // [B,H,DK,T]               (16 MB)
  u16* RH  = (u16*)ws; ws += 4194304;    // [H,T,DK]                 (4 MB)
  u16* Wb  = (u16*)ws; ws += 10485760;   // 5 x 1M bf16 weights      (10 MB)
  u16* CONCAT = (u16*)ws;                // 8 MB

  const size_t M1 = (size_t)1 << 20;

  cvt5w<<<dim3(512, 5), 256, 0, stream>>>(Wq, Wk, Wv, Wr, Wo, Wb);
  gemm_all<<<1408, 256, 0, stream>>>(k, v, q, R, Wb, QH, KH, VT, RH);
  attn14<<<512, 256, 0, stream>>>(QH, KH, VT, RH, u, vb, CONCAT);
  gemm_o<<<512, 256, 0, stream>>>(CONCAT, Wb + 4 * M1, (float*)d_out);
}